// Round 6
// baseline (7724.619 us; speedup 1.0000x reference)
//
#include <hip/hip_runtime.h>
#include <hip/hip_bf16.h>
#include <stdint.h>
#include <stddef.h>

// LSTM: INPUT=512, HIDDEN=1024, BATCH=64, SEQ=512.
// Persistent kernel, BARRIER-FREE slice-granular dataflow:
//   - h published as (tag<<16)|bf16 dwords (tag = exact step), fire-and-forget 8B agent stores.
//   - Each wave STAGES 8 of 32 K-slices (global tagged loads -> validate -> LDS + flag release),
//     and COMPUTES all 32 (spin on LDS flag batch -> ds_read_b128 -> MFMA). Fine-grained
//     dataflow: a slice is gated by its 2 producer WGs only; MFMA overlaps late producers.
//   - 2-parity slice LDS (64KB dynamic + flags); global tag-validation transitively prevents
//     parity races => ZERO per-step barriers.
//   - x A-fragments loaded per-lane directly from global (L2-cached); x-GEMM in slack window.
#define ISZ   512
#define HSZ   1024
#define NBAT  64
#define SEQL  512

typedef __attribute__((ext_vector_type(8))) short  short8;   // 8 x bf16 (4 VGPR)
typedef __attribute__((ext_vector_type(4))) float  floatx4;  // MFMA accumulator
typedef __attribute__((ext_vector_type(4))) int    intx4;
typedef __attribute__((ext_vector_type(4))) unsigned int uintx4;
typedef unsigned long long ull;

__device__ __forceinline__ unsigned short f2bf(float f){     // RNE f32 -> bf16
  unsigned int u = __float_as_uint(f);
  u += 0x7FFFu + ((u >> 16) & 1u);
  return (unsigned short)(u >> 16);
}
__device__ __forceinline__ float sigf(float x){ return 1.0f / (1.0f + __expf(-x)); }
__device__ __forceinline__ float tanh_(float x){ return 2.0f / (1.0f + __expf(-2.0f * x)) - 1.0f; }
__device__ __forceinline__ float sel4(int idx, float a0, float a1, float a2, float a3){
  float r01 = (idx & 1) ? a1 : a0;
  float r23 = (idx & 1) ? a3 : a2;
  return (idx & 2) ? r23 : r01;
}

// ---------------- x f32 -> bf16 ----------------
__global__ __launch_bounds__(256) void k_convert_x(const float* __restrict__ x,
                                                   unsigned short* __restrict__ xb){
  int i = (blockIdx.x * 256 + threadIdx.x) * 8;                      // 8192*256*8 == 64*512*512
  const float4* p = (const float4*)(x + i);
  float4 a = p[0], b = p[1];
  unsigned int w0 = (unsigned int)f2bf(a.x) | ((unsigned int)f2bf(a.y) << 16);
  unsigned int w1 = (unsigned int)f2bf(a.z) | ((unsigned int)f2bf(a.w) << 16);
  unsigned int w2 = (unsigned int)f2bf(b.x) | ((unsigned int)f2bf(b.y) << 16);
  unsigned int w3 = (unsigned int)f2bf(b.z) | ((unsigned int)f2bf(b.w) << 16);
  *(uint4*)(xb + i) = make_uint4(w0, w1, w2, w3);
}

// ---------------- pack W_h/W_x into per-(cg,wave,chunk,lane) B-fragments ----------------
__global__ __launch_bounds__(256) void k_pack_w(const float* __restrict__ Wx,
                                                const float* __restrict__ Wh,
                                                unsigned short* __restrict__ pw){
  int id = blockIdx.x * 256 + threadIdx.x;     // < 786432 = 64*4*48*64
  int lane = id & 63;
  int ch   = (id >> 6) % 48;
  int t2   = (id >> 6) / 48;                   // cg*4 + wv
  int wv = t2 & 3, cg = t2 >> 2;
  int nn = lane & 15, kgrp = lane >> 4;
  int g = nn >> 2, hcl = nn & 3;
  int colh = cg * 16 + wv * 4 + hcl;           // 0..1023
  unsigned short o[8];
  if (ch < 32){
    int k0 = ch * 32 + kgrp * 8;
#pragma unroll
    for (int j = 0; j < 8; ++j) o[j] = f2bf(Wh[(g * 1024 + k0 + j) * 1024 + colh]);
  } else {
    int k0 = (ch - 32) * 32 + kgrp * 8;
#pragma unroll
    for (int j = 0; j < 8; ++j) o[j] = f2bf(Wx[(g * 512 + k0 + j) * 1024 + colh]);
  }
  unsigned int w0 = (unsigned int)o[0] | ((unsigned int)o[1] << 16);
  unsigned int w1 = (unsigned int)o[2] | ((unsigned int)o[3] << 16);
  unsigned int w2 = (unsigned int)o[4] | ((unsigned int)o[5] << 16);
  unsigned int w3 = (unsigned int)o[6] | ((unsigned int)o[7] << 16);
  ((uint4*)pw)[id] = make_uint4(w0, w1, w2, w3);
}

// ---------------- persistent LSTM scan ----------------
__global__ __launch_bounds__(256, 1) void k_scan(const unsigned short* __restrict__ pw,
                                                 const unsigned short* __restrict__ xb,
                                                 const float* __restrict__ bias,
                                                 ull* __restrict__ hq,      // [2][64][512] tagged qwords
                                                 float* __restrict__ out){  // h[64][1024] ++ c[64][1024]
  extern __shared__ __align__(16) char lds[];  // [2 parity][32 slices][1024B] + flags @65536
  int* fl = (int*)(lds + 65536);               // [2][32] slice flags

  const int wg = blockIdx.x;       // 0..255
  const int bg = wg >> 6;          // batch group 0..3 (independent chains)
  const int cg = wg & 63;          // col group 0..63
  const int tid = threadIdx.x;
  const int wv = tid >> 6;         // wave 0..3
  const int lane = tid & 63;
  const int b0 = bg * 16;

  if (tid < 64) fl[tid] = 0;       // init flags before anyone spins
  __syncthreads();                 // the ONLY barrier in this kernel

  // ---- persistent weights in registers, PINNED
  short8 bh[32], bx[16];
  {
    const uint4* base = (const uint4*)pw + (cg * 4 + wv) * 48 * 64 + lane;
#pragma unroll
    for (int c = 0; c < 32; ++c) bh[c] = *(const short8*)(base + c * 64);
#pragma unroll
    for (int c = 0; c < 16; ++c) bx[c] = *(const short8*)(base + (32 + c) * 64);
  }
#pragma unroll
  for (int c = 0; c < 32; ++c) asm volatile("" : "+v"(bh[c]));
#pragma unroll
  for (int c = 0; c < 16; ++c) asm volatile("" : "+v"(bx[c]));

  const int nn = lane & 15;        // MFMA row/col index
  const int G  = nn >> 2;          // gate group (0=i,1=f,2=g,3=o)
  const int hc = nn & 3;           // h-col within wave
  const int kgrp = lane >> 4;      // k-group 0..3
  const int colh = cg * 16 + wv * 4 + hc;
  const float b_i = bias[0 * HSZ + colh];
  const float b_f = bias[1 * HSZ + colh];
  const float b_g = bias[2 * HSZ + colh];
  const float b_o = bias[3 * HSZ + colh];

  // stager geometry: lane -> (row = lane>>2, kg = lane&3); 4 qwords = cols 32q+kg*8..+7
  const int srow = lane >> 2;
  const int skg  = lane & 3;
  const int wslot = (lane ^ ((lane >> 2) & 3)) * 16;                       // LDS write offset in slice
  const int cslot = (((lane & 15) * 4 + (lane >> 4)) ^ (lane & 3)) * 16;   // LDS read offset (A-frag)

  float cst[4] = {0.f, 0.f, 0.f, 0.f};
  floatx4 xp0, xp1;                // parked xg(t)

  // ---- prologue: xg(0) via direct per-lane A-fragment loads (no LDS)
  {
    const unsigned short* xrow = xb + ((size_t)(b0 + nn) * SEQL + 0) * ISZ + kgrp * 8;
    floatx4 a0v = {0.f,0.f,0.f,0.f}, a1v = {0.f,0.f,0.f,0.f};
#pragma unroll
    for (int s = 0; s < 16; ++s){
      short8 a = *(const short8*)(xrow + 32 * s);
      if (s & 1) a1v = __builtin_amdgcn_mfma_f32_16x16x32_bf16(a, bx[s], a1v, 0, 0, 0);
      else       a0v = __builtin_amdgcn_mfma_f32_16x16x32_bf16(a, bx[s], a0v, 0, 0, 0);
    }
    xp0 = a0v; xp1 = a1v;
  }

#pragma unroll 1
  for (int t = 0; t < SEQL; ++t){
    const int p = (t - 1) & 1;     // parity of h(t-1)

    // ---- (A) stage my 8 h slices: tagged global loads -> validate -> LDS + flag
    if (t > 0){
      const unsigned int tg = (unsigned int)(t - 1);
      const ull* hbase = hq + (size_t)p * 32768 + (size_t)(b0 + srow) * 512 + skg * 4;
      ull v[8][4];
#pragma unroll
      for (int j = 0; j < 8; ++j){
        const ull* hb = hbase + 16 * (wv + 4 * j);
#pragma unroll
        for (int e = 0; e < 4; ++e)
          v[j][e] = __hip_atomic_load(hb + e, __ATOMIC_RELAXED, __HIP_MEMORY_SCOPE_AGENT);
      }
#pragma unroll
      for (int j = 0; j < 8; ++j){
        const int q = wv + 4 * j;
        const ull* hb = hbase + 16 * q;
        unsigned int d0, d1, d2, d3, d4, d5, d6, d7;
        for (;;){
          d0 = (unsigned int)v[j][0]; d1 = (unsigned int)(v[j][0] >> 32);
          d2 = (unsigned int)v[j][1]; d3 = (unsigned int)(v[j][1] >> 32);
          d4 = (unsigned int)v[j][2]; d5 = (unsigned int)(v[j][2] >> 32);
          d6 = (unsigned int)v[j][3]; d7 = (unsigned int)(v[j][3] >> 32);
          unsigned int bad = ((d0 >> 16) ^ tg) | ((d1 >> 16) ^ tg) | ((d2 >> 16) ^ tg) |
                             ((d3 >> 16) ^ tg) | ((d4 >> 16) ^ tg) | ((d5 >> 16) ^ tg) |
                             ((d6 >> 16) ^ tg) | ((d7 >> 16) ^ tg);
          if (!bad) break;
#pragma unroll
          for (int e = 0; e < 4; ++e)
            v[j][e] = __hip_atomic_load(hb + e, __ATOMIC_RELAXED, __HIP_MEMORY_SCOPE_AGENT);
        }
        uintx4 pk;
        pk[0] = (d0 & 0xFFFFu) | (d1 << 16);
        pk[1] = (d2 & 0xFFFFu) | (d3 << 16);
        pk[2] = (d4 & 0xFFFFu) | (d5 << 16);
        pk[3] = (d6 & 0xFFFFu) | (d7 << 16);
        *(uintx4*)(lds + (p * 32 + q) * 1024 + wslot) = pk;
        if (lane == 0)
          __hip_atomic_store(&fl[p * 32 + q], t, __ATOMIC_RELEASE, __HIP_MEMORY_SCOPE_WORKGROUP);
      }
    }

    // ---- (B) compute h-GEMM: spin per 4-slice batch, then MFMA
    floatx4 acc0 = xp0, acc1 = xp1;
    if (t > 0){
#pragma unroll
      for (int qb = 0; qb < 8; ++qb){
        volatile intx4* fp = (volatile intx4*)&fl[p * 32 + qb * 4];
        for (;;){
          intx4 f = *fp;
          if (f[0] == t && f[1] == t && f[2] == t && f[3] == t) break;
        }
        __builtin_amdgcn_fence(__ATOMIC_ACQUIRE, "workgroup");
        __builtin_amdgcn_sched_barrier(0);
#pragma unroll
        for (int qq = 0; qq < 4; ++qq){
          const int q = qb * 4 + qq;
          short8 a = *(const short8*)(lds + (p * 32 + q) * 1024 + cslot);
          if (q & 1) acc1 = __builtin_amdgcn_mfma_f32_16x16x32_bf16(a, bh[q], acc1, 0, 0, 0);
          else       acc0 = __builtin_amdgcn_mfma_f32_16x16x32_bf16(a, bh[q], acc0, 0, 0, 0);
        }
      }
    }

    // ---- (C) issue x A-frag loads for t+1 (L2-cached; consumed in slack window)
    const int tx = (t + 1 < SEQL) ? (t + 1) : (SEQL - 1);
    const unsigned short* xrow = xb + ((size_t)(b0 + nn) * SEQL + tx) * ISZ + kgrp * 8;
    short8 xf[16];
#pragma unroll
    for (int s = 0; s < 16; ++s) xf[s] = *(const short8*)(xrow + 32 * s);

    // ---- (D) elementwise combine
    float hvv[4];
#pragma unroll
    for (int r = 0; r < 4; ++r){
      float own = acc0[r] + acc1[r];
      float s4  = __shfl_xor(own, 4);
      float s8  = __shfl_xor(own, 8);
      float s12 = __shfl_xor(own, 12);
      float pi = sel4(G,     own, s4, s8, s12) + b_i;
      float pf = sel4(G ^ 1, own, s4, s8, s12) + b_f;
      float pg = sel4(G ^ 2, own, s4, s8, s12) + b_g;
      float po = sel4(G ^ 3, own, s4, s8, s12) + b_o;
      float iv = sigf(pi), fv = sigf(pf), gv = tanh_(pg), ov = sigf(po);
      float cn = fv * cst[r] + iv * gv;
      cst[r] = cn;
      hvv[r] = ov * tanh_(cn);
      if (G == 0 && t == SEQL - 1){
        int gb = b0 + kgrp * 4 + r;
        out[gb * HSZ + colh] = hvv[r];                 // h_T
        out[NBAT * HSZ + gb * HSZ + colh] = cn;        // c_T
      }
    }

    // ---- (E) publish h(t): 4x4 shfl transpose, 2 tagged fire-and-forget 8B agent stores
    if (G == 0){
      float a0 = hvv[0], a1 = hvv[1], a2 = hvv[2], a3 = hvv[3];
      float s0 = __shfl_xor(a1, 1), s1 = __shfl_xor(a0, 1);
      float s2 = __shfl_xor(a3, 1), s3 = __shfl_xor(a2, 1);
      bool o1 = (nn & 1);
      float t0 = o1 ? s0 : a0,  t1 = o1 ? a1 : s1;
      float t2 = o1 ? s2 : a2,  t3 = o1 ? a3 : s3;
      float u0 = __shfl_xor(t2, 2), u1 = __shfl_xor(t3, 2);
      float u2 = __shfl_xor(t0, 2), u3 = __shfl_xor(t1, 2);
      bool o2 = (nn & 2);
      float w0 = o2 ? u0 : t0,  w1 = o2 ? u1 : t1;
      float w2 = o2 ? t2 : u2,  w3 = o2 ? t3 : u3;
      unsigned int tagw = ((unsigned int)t) << 16;
      unsigned int p0 = (unsigned int)f2bf(w0) | tagw;
      unsigned int p1 = (unsigned int)f2bf(w1) | tagw;
      unsigned int p2 = (unsigned int)f2bf(w2) | tagw;
      unsigned int p3 = (unsigned int)f2bf(w3) | tagw;
      int row = kgrp * 4 + nn;
      size_t off = ((size_t)((t & 1) * 64 + b0 + row)) * 512 + cg * 8 + wv * 2;
      __hip_atomic_store(hq + off,     (ull)p0 | ((ull)p1 << 32),
                         __ATOMIC_RELAXED, __HIP_MEMORY_SCOPE_AGENT);
      __hip_atomic_store(hq + off + 1, (ull)p2 | ((ull)p3 << 32),
                         __ATOMIC_RELAXED, __HIP_MEMORY_SCOPE_AGENT);
    }

    // ---- (F) x-GEMM for t+1 in slack window
    {
      floatx4 a0v = {0.f,0.f,0.f,0.f}, a1v = {0.f,0.f,0.f,0.f};
#pragma unroll
      for (int s = 0; s < 16; ++s){
        if (s & 1) a1v = __builtin_amdgcn_mfma_f32_16x16x32_bf16(xf[s], bx[s], a1v, 0, 0, 0);
        else       a0v = __builtin_amdgcn_mfma_f32_16x16x32_bf16(xf[s], bx[s], a0v, 0, 0, 0);
      }
      xp0 = a0v; xp1 = a1v;
    }
  }
}

extern "C" void kernel_launch(void* const* d_in, const int* in_sizes, int n_in,
                              void* d_out, int out_size, void* d_ws, size_t ws_size,
                              hipStream_t stream){
  (void)in_sizes; (void)n_in; (void)out_size; (void)ws_size;
  const float* x  = (const float*)d_in[0];   // [64][512][512]
  const float* Wx = (const float*)d_in[1];   // [4][512][1024]
  const float* Wh = (const float*)d_in[2];   // [4][1024][1024]
  const float* b  = (const float*)d_in[3];   // [4][1024]
  char* ws = (char*)d_ws;
  unsigned short* pw  = (unsigned short*)ws;                    // 12,582,912 B packed weights
  unsigned short* xbf = (unsigned short*)(ws + 12582912);       // 33,554,432 B x in bf16
  ull*            hq  = (ull*)(ws + 46137344);                  //    524,288 B tagged h double buffer
  float* out = (float*)d_out;

  (void)hipFuncSetAttribute((const void*)k_scan,
                            hipFuncAttributeMaxDynamicSharedMemorySize, 65536 + 256);

  k_convert_x<<<dim3(8192), dim3(256), 0, stream>>>(x, xbf);
  k_pack_w  <<<dim3(3072), dim3(256), 0, stream>>>(Wx, Wh, pw);
  k_scan    <<<dim3(256),  dim3(256), 65536 + 256, stream>>>(pw, xbf, b, hq, out);
}